// Round 6
// baseline (237.202 us; speedup 1.0000x reference)
//
#include <hip/hip_runtime.h>

#define G_VOX  68921      // 41^3
#define GMAX   68920      // last valid element index
#define NSEG   68         // 68 segments of 1024 elements (phase-shifted), 68*1024 = 69632
#define MWORDS 2176       // 32-bit sphere-mask words (69632 bits)
#define RMQ_P  4352       // 68*64 ushort entries per phase
#define NEGV (-1.0e9f)
#define VTH  (-1.0e8f)

__device__ __forceinline__ bool sphere_bit(const float* __restrict__ gxyz, int e) {
    if (e >= G_VOX) return false;
    float gx = gxyz[e * 3 + 0];
    float gy = gxyz[e * 3 + 1];
    float gz = gxyz[e * 3 + 2];
    float s  = __fadd_rn(__fadd_rn(__fmul_rn(gx, gx), __fmul_rn(gy, gy)),
                         __fmul_rn(gz, gz));
    return (__fsqrt_rn(s) <= 6.0f);   // bit-matches np.linalg.norm(grid_xyz) <= 6
}

// ---------------- Kernel 0: sphere word-mask + 4-phase repacked ushort table ----------------
__global__ __launch_bounds__(256) void build_mask(
    const float* __restrict__ gxyz,
    unsigned int* __restrict__ mask,       // [MWORDS] natural bit order
    unsigned short* __restrict__ rmq)      // [4][RMQ_P]: bit(4j+u) = sphere(h +1024s +4p +256j +u)
{
    const int tid  = threadIdx.x;
    const int lane = tid & 63;
    {
        int idx = blockIdx.x * 256 + tid;  // 0..69631
        unsigned long long bal = __ballot(sphere_bit(gxyz, idx));
        if (lane == 0)       mask[idx >> 5] = (unsigned int)bal;
        else if (lane == 32) mask[idx >> 5] = (unsigned int)(bal >> 32);
    }
    int gid = blockIdx.x * 256 + tid;
    if (gid < 4 * RMQ_P) {
        int h    = gid / RMQ_P;
        int rem  = gid - h * RMQ_P;
        int s    = rem >> 6;
        int p    = rem & 63;
        int base = h + 1024 * s + 4 * p;
        unsigned int bits = 0;
        #pragma unroll
        for (int j = 0; j < 4; ++j)
            #pragma unroll
            for (int u = 0; u < 4; ++u)
                if (sphere_bit(gxyz, base + 256 * j + u)) bits |= 1u << (j * 4 + u);
        rmq[gid] = (unsigned short)bits;
    }
}

// ---------------- Fused kernel: one density pass + K=4 pick/NMS, one block per nc ----------------
__global__ __launch_bounds__(512) void fused_peaks(
    const float* __restrict__ density,
    const float* __restrict__ gxyz,
    const unsigned int* __restrict__ maskg,
    const unsigned short* __restrict__ rmq,
    const float* __restrict__ Rm, const float* __restrict__ tp,
    const float* __restrict__ nmask,
    float* __restrict__ out)
{
    __shared__ unsigned int smask[MWORDS + 2];   // +2: 64-bit extracts may touch word wd+1
    __shared__ float sval[NSEG];
    __shared__ int   sidx[NSEG];
    __shared__ int   flag[NSEG];
    __shared__ int   list[104];
    __shared__ int   nlist;
    __shared__ float rv[8];
    __shared__ int   ri[8];
    __shared__ float pval[4];
    __shared__ int   pidx[4];
    __shared__ int   pki[4], pkj[4], pkk[4];

    const int tid  = threadIdx.x;
    const int nc   = blockIdx.x;                 // 0..511
    const int n    = nc >> 2;
    const int h    = (-nc) & 3;                  // phase: nc*68921 + h == 0 (mod 4)
    const int lane = tid & 63;
    const int w    = tid >> 6;                   // wave 0..7
    const float* dens = density + (size_t)nc * G_VOX;

    for (int i = tid; i < MWORDS + 2; i += 512) smask[i] = (i < MWORDS) ? maskg[i] : 0u;
    if (tid < NSEG) flag[tid] = 0;

    // ---- single density pass: wave w owns segments s = w, w+8, ... (1024 elems each) ----
    // lane covers quads e = h + 1024s + 4*lane + 256j, j=0..3; private accumulate, ONE shuffle chain
    for (int s = w; s < NSEG; s += 8) {
        const unsigned int bits16 = rmq[h * RMQ_P + s * 64 + lane];
        const int eb = h + 1024 * s + 4 * lane;
        float bv = NEGV;
        int   bi = eb;
        #pragma unroll
        for (int j = 0; j < 4; ++j) {
            const unsigned int b4 = (bits16 >> (4 * j)) & 0xFu;
            const int e = eb + 256 * j;
            if (b4) {
                if (e + 3 <= GMAX) {
                    float4 d = *reinterpret_cast<const float4*>(dens + e);
                    float v0 = (b4 & 1u) ? d.x : NEGV;
                    float v1 = (b4 & 2u) ? d.y : NEGV;
                    float v2 = (b4 & 4u) ? d.z : NEGV;
                    float v3 = (b4 & 8u) ? d.w : NEGV;
                    if (v0 > bv) { bv = v0; bi = e;     }   // ascending e + strict > = first occurrence
                    if (v1 > bv) { bv = v1; bi = e + 1; }
                    if (v2 > bv) { bv = v2; bi = e + 2; }
                    if (v3 > bv) { bv = v3; bi = e + 3; }
                } else {
                    #pragma unroll
                    for (int u = 0; u < 4; ++u) {
                        if (((b4 >> u) & 1u) && e + u <= GMAX) {
                            float v = dens[e + u];
                            if (v > bv) { bv = v; bi = e + u; }
                        }
                    }
                }
            }
        }
        #pragma unroll
        for (int off = 32; off > 0; off >>= 1) {
            float ov = __shfl_down(bv, off);
            int   oi = __shfl_down(bi, off);
            if (ov > bv || (ov == bv && oi < bi)) { bv = ov; bi = oi; }
        }
        if (lane == 0) { sval[s] = bv; sidx[s] = bi; }
    }
    __syncthreads();

    // ---- K=4 rounds: table argmax + LDS-mask suppression + segment recompute ----
    for (int p = 0; p < 4; ++p) {
        float bv = -INFINITY;
        int   bi = 0x7FFFFFFF;
        if (tid < NSEG) { bv = sval[tid]; bi = sidx[tid]; }
        #pragma unroll
        for (int off = 32; off > 0; off >>= 1) {
            float ov = __shfl_down(bv, off);
            int   oi = __shfl_down(bi, off);
            if (ov > bv || (ov == bv && oi < bi)) { bv = ov; bi = oi; }
        }
        if (lane == 0) { rv[w] = bv; ri[w] = bi; }
        __syncthreads();
        if (w == 0) {
            bv = (lane < 2) ? rv[lane] : -INFINITY;   // only waves 0,1 held table entries
            bi = (lane < 2) ? ri[lane] : 0x7FFFFFFF;
            float ov = __shfl_down(bv, 1);
            int   oi = __shfl_down(bi, 1);
            if (ov > bv || (ov == bv && oi < bi)) { bv = ov; bi = oi; }
            if (lane == 0) {
                pval[p] = bv;
                pidx[p] = bi;
                int pi = bi / 1681;
                int rr = bi - pi * 1681;
                int pj = rr / 41;
                pki[p] = pi; pkj[p] = pj; pkk[p] = rr - pj * 41;
                nlist = 0;
            }
        }
        __syncthreads();

        if (p < 3 && pval[p] > VTH) {
            // clear 7x7x7 Chebyshev cube bits in LDS mask; collect affected segments
            if (tid < 49) {
                int di = tid / 7 - 3, dj = tid % 7 - 3;
                int ii = pki[p] + di, jj = pkj[p] + dj;
                if (ii >= 0 && ii <= 40 && jj >= 0 && jj <= 40) {
                    int k0 = pkk[p] - 3; if (k0 < 0)  k0 = 0;
                    int k1 = pkk[p] + 3; if (k1 > 40) k1 = 40;
                    int b0  = ii * 1681 + jj * 41 + k0;
                    int cnt = k1 - k0 + 1;
                    unsigned long long m = ((1ull << cnt) - 1ull) << (b0 & 31);
                    int w0 = b0 >> 5;
                    atomicAnd(&smask[w0], ~(unsigned int)m);
                    unsigned int hi = (unsigned int)(m >> 32);
                    if (hi) atomicAnd(&smask[w0 + 1], ~hi);
                    int s0 = (b0 > h) ? (b0 - h) >> 10 : 0;
                    int s1 = (b0 + cnt - 1 > h) ? (b0 + cnt - 1 - h) >> 10 : 0;
                    if (atomicMax(&flag[s0], p + 1) < p + 1) {
                        int q = atomicAdd(&nlist, 1); list[q] = s0;
                    }
                    if (s1 != s0 && atomicMax(&flag[s1], p + 1) < p + 1) {
                        int q = atomicAdd(&nlist, 1); list[q] = s1;
                    }
                }
            }
            __syncthreads();
            // recompute flagged segments from post-suppression LDS mask: one wave per entry
            const int cnt = nlist;
            for (int q = w; q < cnt; q += 8) {
                const int s  = list[q];
                const int eb = h + 1024 * s + 4 * lane;
                float bv2 = NEGV;
                int   bi2 = eb;
                #pragma unroll
                for (int j = 0; j < 4; ++j) {
                    const int e = eb + 256 * j;
                    const int wd = e >> 5, sh = e & 31;
                    unsigned long long mw = ((unsigned long long)smask[wd + 1] << 32) | smask[wd];
                    const unsigned int b4 = (unsigned int)(mw >> sh) & 0xFu;
                    if (b4) {
                        if (e + 3 <= GMAX) {
                            float4 d = *reinterpret_cast<const float4*>(dens + e);
                            float v0 = (b4 & 1u) ? d.x : NEGV;
                            float v1 = (b4 & 2u) ? d.y : NEGV;
                            float v2 = (b4 & 4u) ? d.z : NEGV;
                            float v3 = (b4 & 8u) ? d.w : NEGV;
                            if (v0 > bv2) { bv2 = v0; bi2 = e;     }
                            if (v1 > bv2) { bv2 = v1; bi2 = e + 1; }
                            if (v2 > bv2) { bv2 = v2; bi2 = e + 2; }
                            if (v3 > bv2) { bv2 = v3; bi2 = e + 3; }
                        } else {
                            #pragma unroll
                            for (int u = 0; u < 4; ++u) {
                                if (((b4 >> u) & 1u) && e + u <= GMAX) {
                                    float v = dens[e + u];
                                    if (v > bv2) { bv2 = v; bi2 = e + u; }
                                }
                            }
                        }
                    }
                }
                #pragma unroll
                for (int off = 32; off > 0; off >>= 1) {
                    float ov = __shfl_down(bv2, off);
                    int   oi = __shfl_down(bi2, off);
                    if (ov > bv2 || (ov == bv2 && oi < bi2)) { bv2 = ov; bi2 = oi; }
                }
                if (lane == 0) { sval[s] = bv2; sidx[s] = bi2; }
            }
        }
        __syncthreads();
    }

    // ---- epilogue: one peak per thread ----
    if (tid < 4) {
        const int k   = tid;
        const float val = pval[k];
        const int   idx = pidx[k];
        const bool valid = val > VTH;
        float gx = 0.0f, gy = 0.0f, gz = 0.0f;
        if (valid) {
            gx = gxyz[idx * 3 + 0];
            gy = gxyz[idx * 3 + 1];
            gz = gxyz[idx * 3 + 2];
        }
        const float nm = nmask[n];
        const float* R = Rm + n * 9;
        const float* t = tp + n * 3;
        float wx = R[0] * gx + R[1] * gy + R[2] * gz + t[0];
        float wy = R[3] * gx + R[4] * gy + R[5] * gz + t[1];
        float wz = R[6] * gx + R[7] * gy + R[8] * gz + t[2];

        const size_t o3 = ((size_t)nc * 4 + k) * 3;
        out[o3 + 0] = gx * nm;                       // coords_local [1,128,4,4,3]
        out[o3 + 1] = gy * nm;
        out[o3 + 2] = gz * nm;
        out[6144 + o3 + 0] = wx * nm;                // coords_global
        out[6144 + o3 + 1] = wy * nm;
        out[6144 + o3 + 2] = wz * nm;
        const size_t o1 = (size_t)nc * 4 + k;
        out[12288 + o1] = (valid ? val : NEGV) * nm; // scores
        out[14336 + o1] = (valid && nm != 0.0f) ? 1.0f : 0.0f;  // mask
    }
}

extern "C" void kernel_launch(void* const* d_in, const int* in_sizes, int n_in,
                              void* d_out, int out_size, void* d_ws, size_t ws_size,
                              hipStream_t stream) {
    const float* density  = (const float*)d_in[0];  // [1,128,4,G] f32
    const float* grid_xyz = (const float*)d_in[1];  // [G,3] f32
    const float* Rm    = (const float*)d_in[4];     // [1,128,3,3] f32
    const float* tpos  = (const float*)d_in[5];     // [1,128,3] f32
    const float* nmask = (const float*)d_in[6];     // [1,128] f32
    float* out = (float*)d_out;                     // 16384 f32

    unsigned int*   mask = (unsigned int*)d_ws;                     // 8704 B
    unsigned short* rmq  = (unsigned short*)((char*)d_ws + 8704);   // 4*4352*2 = 34816 B

    build_mask<<<dim3(272), dim3(256), 0, stream>>>(grid_xyz, mask, rmq);
    fused_peaks<<<dim3(512), dim3(512), 0, stream>>>(density, grid_xyz, mask, rmq,
                                                     Rm, tpos, nmask, out);
}